// Round 20
// baseline (138.565 us; speedup 1.0000x reference)
//
#include <hip/hip_runtime.h>

typedef __attribute__((ext_vector_type(8))) short bf16x8;
typedef __attribute__((ext_vector_type(4))) float f32x4;
typedef __attribute__((ext_vector_type(16))) float f32x16;
typedef unsigned short u16;
typedef unsigned int u32;

#define MFMA16(a,b,c) __builtin_amdgcn_mfma_f32_16x16x32_bf16((a),(b),(c),0,0,0)
#define MFMA32(a,b,c) __builtin_amdgcn_mfma_f32_32x32x16_bf16((a),(b),(c),0,0,0)

#if __has_builtin(__builtin_amdgcn_exp2f)
#define EXP2(x) __builtin_amdgcn_exp2f(x)
#else
#define EXP2(x) __expf((x) * 0.6931471805599453f)
#endif

// f32 -> bf16 round-to-nearest-even
__device__ __forceinline__ u16 f2bf(float f) {
  u32 u = __builtin_bit_cast(u32, f);
  u += 0x7FFFu + ((u >> 16) & 1u);
  return (u16)(u >> 16);
}

// packed pair f32x2 -> bf16x2 (RNE) in one instruction
__device__ __forceinline__ u32 cvtpk(float lo, float hi) {
  u32 r;
  asm("v_cvt_pk_bf16_f32 %0, %1, %2" : "=v"(r) : "v"(lo), "v"(hi));
  return r;
}

// half-wave register exchange (verified pairing, R12)
__device__ __forceinline__ void swap32(u32& a, u32& b) {
#if __has_builtin(__builtin_amdgcn_permlane32_swap)
  auto r = __builtin_amdgcn_permlane32_swap((int)a, (int)b, false, false);
  a = (u32)r[0];
  b = (u32)r[1];
#else
  u32 pa = __shfl_xor(a, 32), pb = __shfl_xor(b, 32);
  bool lo = ((threadIdx.x & 32) == 0);
  u32 na = lo ? a : pb;
  u32 nb = lo ? pa : b;
  a = na; b = nb;
#endif
}

// async 16B global -> LDS (dest must be wave-uniform base + lane*16)
__device__ __forceinline__ void gload16(const u16* g, u16* l) {
  __builtin_amdgcn_global_load_lds(
      (const __attribute__((address_space(1))) u32*)(const void*)g,
      (__attribute__((address_space(3))) u32*)(void*)l, 16, 0, 0);
}

// swizzled 16B read from a [R][64] bf16 LDS tile (chunk = 8-elem unit)
__device__ __forceinline__ bf16x8 ldsfrag(const u16* lds, int row, int chunk) {
  return *(const bf16x8*)(lds + row * 64 + ((chunk ^ (row & 7)) << 3));
}

// ---------------- x f32 -> bf16 ----------------
__global__ __launch_bounds__(256) void convert_x(const float* __restrict__ in,
                                                 u16* __restrict__ out, int n4) {
  int i = blockIdx.x * blockDim.x + threadIdx.x;
  int stride = gridDim.x * blockDim.x;
  for (; i < n4; i += stride) {
    float4 v = ((const float4*)in)[i];
    u32 lo = (u32)f2bf(v.x) | ((u32)f2bf(v.y) << 16);
    u32 hi = (u32)f2bf(v.z) | ((u32)f2bf(v.w) << 16);
    uint2 pv; pv.x = lo; pv.y = hi;
    ((uint2*)out)[i] = pv;
  }
}

// ---------------- W [R][C] f32 -> Wt [C][R] bf16 (R = 1024) ----------------
__global__ __launch_bounds__(256) void transpose_w(const float* __restrict__ in,
                                                   u16* __restrict__ out,
                                                   int R, int C) {
  __shared__ float t[32][33];
  int c0 = blockIdx.x * 32, r0 = blockIdx.y * 32;
  int tc = threadIdx.x & 31, tr = threadIdx.x >> 5;  // tr in 0..7
#pragma unroll
  for (int j = 0; j < 4; ++j) {
    int r = tr + j * 8;
    t[r][tc] = in[(size_t)(r0 + r) * C + c0 + tc];
  }
  __syncthreads();
#pragma unroll
  for (int j = 0; j < 4; ++j) {
    int cc = tr + j * 8;
    out[(size_t)(c0 + cc) * R + r0 + tc] = f2bf(t[tc][cc]);
  }
}

// ---------------- GEMM: 128x128, 3-buffer, ONE barrier per K-step (R18) ----
template <int MODE>
__global__ __launch_bounds__(256, 3) void gemm_k(
    const u16* __restrict__ A, const u16* __restrict__ Bt,
    const float* __restrict__ bias,
    u16* __restrict__ Qo, u16* __restrict__ Ko, u16* __restrict__ Vt,
    float* __restrict__ Of) {
  __shared__ alignas(16) u16 As[3][4096];
  __shared__ alignas(16) u16 Bs[3][4096];
  const int tid = threadIdx.x;
  const int wid = tid >> 6, lane = tid & 63;
  const int g = lane >> 4, lr = lane & 15;
  const int m0 = blockIdx.y * 128, n0 = blockIdx.x * 128;
  const int wr = (wid >> 1) * 64, wc = (wid & 1) * 64;

  f32x4 acc[4][4];
#pragma unroll
  for (int i = 0; i < 4; ++i)
#pragma unroll
    for (int j = 0; j < 4; ++j) acc[i][j] = (f32x4){0.f, 0.f, 0.f, 0.f};

  const u16* Ab = A + (size_t)m0 * 1024;
  const u16* Bb = Bt + (size_t)n0 * 1024;

  const int srow = tid >> 2, sc = tid & 3;
  auto stage = [&](int buf, int kt) {
#pragma unroll
    for (int i = 0; i < 2; ++i) {
      int s = tid + i * 256;
      int row = srow + i * 64;
      int csrc = sc ^ ((row >> 1) & 3);
      gload16(Ab + (size_t)row * 1024 + kt + csrc * 8, As[buf] + s * 8);
      gload16(Bb + (size_t)row * 1024 + kt + csrc * 8, Bs[buf] + s * 8);
    }
  };

  stage(0, 0);
  stage(1, 32);
  int cur = 0;
  for (int ki = 0; ki < 32; ++ki) {
    if (ki < 31) asm volatile("s_waitcnt vmcnt(4)" ::: "memory");
    else         asm volatile("s_waitcnt vmcnt(0)" ::: "memory");
    __builtin_amdgcn_sched_barrier(0);
    __builtin_amdgcn_s_barrier();     // st(ki) landed everywhere; reads of
    __builtin_amdgcn_sched_barrier(0);//  buf (ki-1)%3 complete block-wide
    if (ki + 2 < 32) {
      int nxt = cur + 2; if (nxt >= 3) nxt -= 3;
      stage(nxt, (ki + 2) * 32);      // safe: target's readers all done
    }

    bf16x8 af[4], bfr[4];
#pragma unroll
    for (int i = 0; i < 4; ++i) {
      int row = wr + i * 16 + lr;
      int slot = g ^ ((row >> 1) & 3);
      af[i] = *(const bf16x8*)(As[cur] + row * 32 + slot * 8);
    }
#pragma unroll
    for (int j = 0; j < 4; ++j) {
      int row = wc + j * 16 + lr;
      int slot = g ^ ((row >> 1) & 3);
      bfr[j] = *(const bf16x8*)(Bs[cur] + row * 32 + slot * 8);
    }
    __builtin_amdgcn_s_setprio(1);
#pragma unroll
    for (int i = 0; i < 4; ++i)
#pragma unroll
      for (int j = 0; j < 4; ++j)
        acc[i][j] = MFMA16(af[i], bfr[j], acc[i][j]);
    __builtin_amdgcn_s_setprio(0);

    cur += 1; if (cur >= 3) cur -= 3;
  }

  if constexpr (MODE == 1) {
#pragma unroll
    for (int i = 0; i < 4; ++i) {
      int row = m0 + wr + i * 16 + g * 4;
#pragma unroll
      for (int j = 0; j < 4; ++j) {
        int col = n0 + wc + j * 16 + lr;
        float bv = bias[col];
#pragma unroll
        for (int r = 0; r < 4; ++r)
          Of[(size_t)(row + r) * 1024 + col] = acc[i][j][r] + bv;
      }
    }
  } else {
    const int sel = n0 >> 10;
#pragma unroll
    for (int i = 0; i < 4; ++i) {
      int row = m0 + wr + i * 16 + g * 4;
      int b = row >> 11, s = row & 2047;
#pragma unroll
      for (int j = 0; j < 4; ++j) {
        int col = n0 + wc + j * 16 + lr;
        float bv = bias[col];
        int nn = col & 1023;
        int h = nn >> 6, hd = nn & 63;
        if (sel == 2) {
          u16 pk[4];
#pragma unroll
          for (int r = 0; r < 4; ++r) pk[r] = f2bf(acc[i][j][r] + bv);
          uint2 pv;
          pv.x = (u32)pk[0] | ((u32)pk[1] << 16);
          pv.y = (u32)pk[2] | ((u32)pk[3] << 16);
          *(uint2*)(Vt + (size_t)((b * 16 + h) * 64 + hd) * 2048 + s) = pv;
        } else {
          u16* dst = (sel == 0) ? Qo : Ko;
#pragma unroll
          for (int r = 0; r < 4; ++r)
            dst[(size_t)((b * 16 + h) * 2048 + s + r) * 64 + hd] =
                f2bf(acc[i][j][r] + bv);
        }
      }
    }
  }
}

// ---------------- flash attention: K via LDS ring, V DIRECT from global ----
// R20 = R18 structure (R12 math, 4-buffer K ring, one barrier/iter) with V
// loaded straight from global into registers (L2-resident; same claimed
// contiguous-8 layout as the old LDS path -> cancellation argument intact).
// Halves LDS read traffic (16 -> 8 b128/wave-tile) and staging writes.
// vmcnt: stage = 2 K-loads; V = 8 reg loads issued top-of-iter. Steady
// outstanding at wait = st(t+1)(2) + st(t+2)(2) + V(t)(8) = 12 -> vmcnt(12)
// retires st(t) (t=0 also retires qf, pinned oldest). t=30 -> vmcnt(10);
// t=31 -> vmcnt(8). Compiler auto-waits V regs before PV.
__global__ __launch_bounds__(256, 2) void attn_k(const u16* __restrict__ Q,
                                                 const u16* __restrict__ K,
                                                 const u16* __restrict__ Vt,
                                                 u16* __restrict__ O) {
  __shared__ alignas(16) u16 Ks[4][4096];   // 4 bufs [kv][hd], chunk-XOR swizzled
  const int tid = threadIdx.x;
  const int wid = tid >> 6, lane = tid & 63;
  const int l31 = lane & 31, b5 = lane >> 5;
  const int p = blockIdx.x;
  const int l = (p & 7) * 64 + (p >> 3);  // XCD chunk swizzle (512 % 8 == 0)
  const int qt = l & 15, bh = l >> 4;
  const u16* Qh = Q + (size_t)bh * 2048 * 64;
  const u16* Kh = K + (size_t)bh * 2048 * 64;
  const u16* Vh = Vt + (size_t)bh * 64 * 2048;

  // Q B-frags FIRST (pinned oldest in the per-lane VMEM queue)
  const int qbase = qt * 128 + wid * 32;
  const u16* qp = Qh + (size_t)(qbase + l31) * 64 + b5 * 8;
  bf16x8 qf[4];
#pragma unroll
  for (int c = 0; c < 4; ++c) qf[c] = *(const bf16x8*)(qp + 16 * c);
  __builtin_amdgcn_sched_barrier(0);

  auto stage = [&](int buf, int t) {
#pragma unroll
    for (int i = 0; i < 2; ++i) {
      int s = tid + i * 256;
      int row = s >> 3, c = (s & 7) ^ (row & 7);
      gload16(Kh + (t * 64 + row) * 64 + c * 8, Ks[buf] + s * 8);
    }
  };
  stage(0, 0);
  stage(1, 1);

  // per-lane V row bases (claimed contiguous-8 layout, same as old LDS path)
  const u16* vrow0 = Vh + (size_t)l31 * 2048 + b5 * 8;
  const u16* vrow1 = Vh + (size_t)(32 + l31) * 2048 + b5 * 8;

  f32x16 accO0, accO1;   // rows = hd (crow map), cols = q = lane (lane-local)
#pragma unroll
  for (int r = 0; r < 16; ++r) { accO0[r] = 0.f; accO1[r] = 0.f; }
  float mraw = -1e30f;  // running max for q=l31 (raw-score units)
  float mC = 0.f;       // mraw * C2 (exp2 domain)
  float lsum = 0.f;     // per-lane partial denominator

  const float C2 = 0.125f * 1.44269504088896f;  // SCALE * log2(e)

  int cur = 0;
  for (int t = 0; t < 32; ++t) {
    if (t + 2 < 32) {
      int nxt = cur + 2; if (nxt >= 4) nxt -= 4;
      stage(nxt, t + 2);
    }
    // V fragments for THIS tile: direct global loads (L2-hot), consumed
    // after QK+softmax (~600 cy of cover; compiler inserts the data wait).
    bf16x8 v0[4], v1[4];
    {
      const int kv0 = t * 64;
#pragma unroll
      for (int c = 0; c < 4; ++c) {
        v0[c] = *(const bf16x8*)(vrow0 + kv0 + 16 * c);
        v1[c] = *(const bf16x8*)(vrow1 + kv0 + 16 * c);
      }
    }
    if (t < 30)       asm volatile("s_waitcnt vmcnt(12)" ::: "memory");
    else if (t == 30) asm volatile("s_waitcnt vmcnt(10)" ::: "memory");
    else              asm volatile("s_waitcnt vmcnt(8)" ::: "memory");
    __builtin_amdgcn_sched_barrier(0);
    __builtin_amdgcn_s_barrier();   // all waves' K stage(t) complete
    __builtin_amdgcn_sched_barrier(0);

    const u16* Kc = Ks[cur];

    // QK^T swapped (A=K, B=Q): same claimed layout on both operands.
    f32x16 s0, s1;
#pragma unroll
    for (int r = 0; r < 16; ++r) { s0[r] = 0.f; s1[r] = 0.f; }
    __builtin_amdgcn_s_setprio(1);
#pragma unroll
    for (int c = 0; c < 4; ++c) {
      bf16x8 k0 = ldsfrag(Kc, l31, 2 * c + b5);
      bf16x8 k1 = ldsfrag(Kc, 32 + l31, 2 * c + b5);
      s0 = MFMA32(k0, qf[c], s0);
      s1 = MFMA32(k1, qf[c], s1);
    }
    __builtin_amdgcn_s_setprio(0);

    // lane-local max over this lane's 32 kv values (q = l31)
    float rmax;
    {
      float a0 = fmaxf(fmaxf(s0[0], s0[1]), fmaxf(s0[2], s0[3]));
      float a1 = fmaxf(fmaxf(s0[4], s0[5]), fmaxf(s0[6], s0[7]));
      float a2 = fmaxf(fmaxf(s0[8], s0[9]), fmaxf(s0[10], s0[11]));
      float a3 = fmaxf(fmaxf(s0[12], s0[13]), fmaxf(s0[14], s0[15]));
      float b0 = fmaxf(fmaxf(s1[0], s1[1]), fmaxf(s1[2], s1[3]));
      float b1 = fmaxf(fmaxf(s1[4], s1[5]), fmaxf(s1[6], s1[7]));
      float b2 = fmaxf(fmaxf(s1[8], s1[9]), fmaxf(s1[10], s1[11]));
      float b3 = fmaxf(fmaxf(s1[12], s1[13]), fmaxf(s1[14], s1[15]));
      rmax = fmaxf(fmaxf(fmaxf(a0, a1), fmaxf(a2, a3)),
                   fmaxf(fmaxf(b0, b1), fmaxf(b2, b3)));
    }
    rmax = fmaxf(rmax, __shfl_xor(rmax, 32));  // combine the two kv-subsets

    // defer-max: accO cols = q = lane -> alpha is LANE-LOCAL.
    if (__any(rmax > mraw + 64.f)) {
      float mn = fmaxf(mraw, rmax);
      float al = EXP2((mraw - mn) * C2);
      mraw = mn;
      mC = mn * C2;
      lsum *= al;
#pragma unroll
      for (int r = 0; r < 16; ++r) {
        accO0[r] *= al;
        accO1[r] *= al;
      }
    }

    // P = exp2(s*C2 - mC); pack reg-adjacent (=kv-adjacent) pairs into words
    u32 w0[8], w1[8];
#pragma unroll
    for (int i = 0; i < 8; ++i) {
      float p0 = EXP2(__builtin_fmaf(s0[2 * i], C2, -mC));
      float p1 = EXP2(__builtin_fmaf(s0[2 * i + 1], C2, -mC));
      float p2 = EXP2(__builtin_fmaf(s1[2 * i], C2, -mC));
      float p3 = EXP2(__builtin_fmaf(s1[2 * i + 1], C2, -mC));
      lsum += (p0 + p1) + (p2 + p3);
      w0[i] = cvtpk(p0, p1);
      w1[i] = cvtpk(p2, p3);
    }

    // PV swapped: per 16-kv chunk c, P B-frag via 2 permlane32_swap;
    // A = V rows from REGISTERS (global-loaded, claimed layout -> cancels).
    __builtin_amdgcn_s_setprio(1);
#pragma unroll
    for (int c = 0; c < 4; ++c) {
      u32 a0, a1, b0, b1;
      if (c == 0)      { a0 = w0[0]; b0 = w0[2]; a1 = w0[1]; b1 = w0[3]; }
      else if (c == 1) { a0 = w0[4]; b0 = w0[6]; a1 = w0[5]; b1 = w0[7]; }
      else if (c == 2) { a0 = w1[0]; b0 = w1[2]; a1 = w1[1]; b1 = w1[3]; }
      else             { a0 = w1[4]; b0 = w1[6]; a1 = w1[5]; b1 = w1[7]; }
      swap32(a0, b0);
      swap32(a1, b1);
      uint4 u; u.x = a0; u.y = a1; u.z = b0; u.w = b1;
      bf16x8 pf = __builtin_bit_cast(bf16x8, u);
      accO0 = MFMA32(v0[c], pf, accO0);
      accO1 = MFMA32(v1[c], pf, accO1);
    }
    __builtin_amdgcn_s_setprio(0);

    // no second barrier: 4-buffer K ring (disjointness proof in R17)
    cur += 1; if (cur >= 4) cur -= 4;
  }

  // finish: denominator for q=l31 is lane-local after one half-exchange
  float ls = lsum + __shfl_xor(lsum, 32);
  float inv = 1.f / ls;
  const int b = bh >> 4, h = bh & 15;
  u16* orow = O + (size_t)(b * 2048 + qbase + l31) * 1024 + h * 64;
#pragma unroll
  for (int rg = 0; rg < 4; ++rg) {
    int hd0 = 8 * rg + 4 * b5;   // accO rows rg*4..rg*4+3 -> hd0..hd0+3
    uint2 o0, o1;
    o0.x = cvtpk(accO0[4 * rg + 0] * inv, accO0[4 * rg + 1] * inv);
    o0.y = cvtpk(accO0[4 * rg + 2] * inv, accO0[4 * rg + 3] * inv);
    o1.x = cvtpk(accO1[4 * rg + 0] * inv, accO1[4 * rg + 1] * inv);
    o1.y = cvtpk(accO1[4 * rg + 2] * inv, accO1[4 * rg + 3] * inv);
    *(uint2*)(orow + hd0) = o0;
    *(uint2*)(orow + 32 + hd0) = o1;
  }
}

extern "C" void kernel_launch(void* const* d_in, const int* in_sizes, int n_in,
                              void* d_out, int out_size, void* d_ws, size_t ws_size,
                              hipStream_t stream) {
  (void)in_sizes; (void)n_in; (void)out_size; (void)ws_size;
  const float* x = (const float*)d_in[0];
  const float* Wqkv = (const float*)d_in[1];
  const float* bqkv = (const float*)d_in[2];
  const float* Wproj = (const float*)d_in[3];
  const float* bproj = (const float*)d_in[4];
  float* out = (float*)d_out;

  char* ws = (char*)d_ws;
  size_t off = 0;
  auto alloc = [&](size_t bytes) {
    void* p = ws + off;
    off += (bytes + 255) & ~(size_t)255;
    return p;
  };
  u16* xb     = (u16*)alloc((size_t)4096 * 1024 * 2);
  u16* Wqkvt  = (u16*)alloc((size_t)3072 * 1024 * 2);
  u16* Wprojt = (u16*)alloc((size_t)1024 * 1024 * 2);
  u16* Qb     = (u16*)alloc((size_t)32 * 2048 * 64 * 2);
  u16* Kb     = (u16*)alloc((size_t)32 * 2048 * 64 * 2);
  u16* Vtb    = (u16*)alloc((size_t)32 * 64 * 2048 * 2);
  u16* AOb    = (u16*)alloc((size_t)4096 * 1024 * 2);

  convert_x<<<2048, 256, 0, stream>>>(x, xb, 4096 * 1024 / 4);
  transpose_w<<<dim3(96, 32), 256, 0, stream>>>(Wqkv, Wqkvt, 1024, 3072);
  transpose_w<<<dim3(32, 32), 256, 0, stream>>>(Wproj, Wprojt, 1024, 1024);
  gemm_k<0><<<dim3(24, 32), 256, 0, stream>>>(xb, Wqkvt, bqkv, Qb, Kb, Vtb, nullptr);
  attn_k<<<512, 256, 0, stream>>>(Qb, Kb, Vtb, AOb);
  gemm_k<1><<<dim3(8, 32), 256, 0, stream>>>(AOb, Wprojt, bproj, nullptr, nullptr, nullptr, out);
}

// Round 21
// 123.327 us; speedup vs baseline: 1.1236x; 1.1236x over previous
//
#include <hip/hip_runtime.h>

typedef __attribute__((ext_vector_type(8))) short bf16x8;
typedef __attribute__((ext_vector_type(4))) float f32x4;
typedef __attribute__((ext_vector_type(16))) float f32x16;
typedef unsigned short u16;
typedef unsigned int u32;

#define MFMA16(a,b,c) __builtin_amdgcn_mfma_f32_16x16x32_bf16((a),(b),(c),0,0,0)
#define MFMA32(a,b,c) __builtin_amdgcn_mfma_f32_32x32x16_bf16((a),(b),(c),0,0,0)

#if __has_builtin(__builtin_amdgcn_exp2f)
#define EXP2(x) __builtin_amdgcn_exp2f(x)
#else
#define EXP2(x) __expf((x) * 0.6931471805599453f)
#endif

// f32 -> bf16 round-to-nearest-even
__device__ __forceinline__ u16 f2bf(float f) {
  u32 u = __builtin_bit_cast(u32, f);
  u += 0x7FFFu + ((u >> 16) & 1u);
  return (u16)(u >> 16);
}

// packed pair f32x2 -> bf16x2 (RNE) in one instruction
__device__ __forceinline__ u32 cvtpk(float lo, float hi) {
  u32 r;
  asm("v_cvt_pk_bf16_f32 %0, %1, %2" : "=v"(r) : "v"(lo), "v"(hi));
  return r;
}

// half-wave register exchange (verified pairing, R12)
__device__ __forceinline__ void swap32(u32& a, u32& b) {
#if __has_builtin(__builtin_amdgcn_permlane32_swap)
  auto r = __builtin_amdgcn_permlane32_swap((int)a, (int)b, false, false);
  a = (u32)r[0];
  b = (u32)r[1];
#else
  u32 pa = __shfl_xor(a, 32), pb = __shfl_xor(b, 32);
  bool lo = ((threadIdx.x & 32) == 0);
  u32 na = lo ? a : pb;
  u32 nb = lo ? pa : b;
  a = na; b = nb;
#endif
}

// async 16B global -> LDS (dest must be wave-uniform base + lane*16)
__device__ __forceinline__ void gload16(const u16* g, u16* l) {
  __builtin_amdgcn_global_load_lds(
      (const __attribute__((address_space(1))) u32*)(const void*)g,
      (__attribute__((address_space(3))) u32*)(void*)l, 16, 0, 0);
}

// swizzled 16B read from a [R][64] bf16 LDS tile (chunk = 8-elem unit)
__device__ __forceinline__ bf16x8 ldsfrag(const u16* lds, int row, int chunk) {
  return *(const bf16x8*)(lds + row * 64 + ((chunk ^ (row & 7)) << 3));
}

// ---------------- x f32 -> bf16 ----------------
__global__ __launch_bounds__(256) void convert_x(const float* __restrict__ in,
                                                 u16* __restrict__ out, int n4) {
  int i = blockIdx.x * blockDim.x + threadIdx.x;
  int stride = gridDim.x * blockDim.x;
  for (; i < n4; i += stride) {
    float4 v = ((const float4*)in)[i];
    u32 lo = (u32)f2bf(v.x) | ((u32)f2bf(v.y) << 16);
    u32 hi = (u32)f2bf(v.z) | ((u32)f2bf(v.w) << 16);
    uint2 pv; pv.x = lo; pv.y = hi;
    ((uint2*)out)[i] = pv;
  }
}

// ---------------- W [R][C] f32 -> Wt [C][R] bf16 (R = 1024) ----------------
__global__ __launch_bounds__(256) void transpose_w(const float* __restrict__ in,
                                                   u16* __restrict__ out,
                                                   int R, int C) {
  __shared__ float t[32][33];
  int c0 = blockIdx.x * 32, r0 = blockIdx.y * 32;
  int tc = threadIdx.x & 31, tr = threadIdx.x >> 5;  // tr in 0..7
#pragma unroll
  for (int j = 0; j < 4; ++j) {
    int r = tr + j * 8;
    t[r][tc] = in[(size_t)(r0 + r) * C + c0 + tc];
  }
  __syncthreads();
#pragma unroll
  for (int j = 0; j < 4; ++j) {
    int cc = tr + j * 8;
    out[(size_t)(c0 + cc) * R + r0 + tc] = f2bf(t[tc][cc]);
  }
}

// ---------------- qkv GEMM: 128x128, 3-buffer, ONE barrier per K-step (R18)
__global__ __launch_bounds__(256, 3) void gemm_qkv(
    const u16* __restrict__ A, const u16* __restrict__ Bt,
    const float* __restrict__ bias,
    u16* __restrict__ Qo, u16* __restrict__ Ko, u16* __restrict__ Vt) {
  __shared__ alignas(16) u16 As[3][4096];
  __shared__ alignas(16) u16 Bs[3][4096];
  const int tid = threadIdx.x;
  const int wid = tid >> 6, lane = tid & 63;
  const int g = lane >> 4, lr = lane & 15;
  const int m0 = blockIdx.y * 128, n0 = blockIdx.x * 128;
  const int wr = (wid >> 1) * 64, wc = (wid & 1) * 64;

  f32x4 acc[4][4];
#pragma unroll
  for (int i = 0; i < 4; ++i)
#pragma unroll
    for (int j = 0; j < 4; ++j) acc[i][j] = (f32x4){0.f, 0.f, 0.f, 0.f};

  const u16* Ab = A + (size_t)m0 * 1024;
  const u16* Bb = Bt + (size_t)n0 * 1024;

  const int srow = tid >> 2, sc = tid & 3;
  auto stage = [&](int buf, int kt) {
#pragma unroll
    for (int i = 0; i < 2; ++i) {
      int s = tid + i * 256;
      int row = srow + i * 64;
      int csrc = sc ^ ((row >> 1) & 3);
      gload16(Ab + (size_t)row * 1024 + kt + csrc * 8, As[buf] + s * 8);
      gload16(Bb + (size_t)row * 1024 + kt + csrc * 8, Bs[buf] + s * 8);
    }
  };

  stage(0, 0);
  stage(1, 32);
  int cur = 0;
  for (int ki = 0; ki < 32; ++ki) {
    if (ki < 31) asm volatile("s_waitcnt vmcnt(4)" ::: "memory");
    else         asm volatile("s_waitcnt vmcnt(0)" ::: "memory");
    __builtin_amdgcn_sched_barrier(0);
    __builtin_amdgcn_s_barrier();
    __builtin_amdgcn_sched_barrier(0);
    if (ki + 2 < 32) {
      int nxt = cur + 2; if (nxt >= 3) nxt -= 3;
      stage(nxt, (ki + 2) * 32);
    }

    bf16x8 af[4], bfr[4];
#pragma unroll
    for (int i = 0; i < 4; ++i) {
      int row = wr + i * 16 + lr;
      int slot = g ^ ((row >> 1) & 3);
      af[i] = *(const bf16x8*)(As[cur] + row * 32 + slot * 8);
    }
#pragma unroll
    for (int j = 0; j < 4; ++j) {
      int row = wc + j * 16 + lr;
      int slot = g ^ ((row >> 1) & 3);
      bfr[j] = *(const bf16x8*)(Bs[cur] + row * 32 + slot * 8);
    }
    __builtin_amdgcn_s_setprio(1);
#pragma unroll
    for (int i = 0; i < 4; ++i)
#pragma unroll
      for (int j = 0; j < 4; ++j)
        acc[i][j] = MFMA16(af[i], bfr[j], acc[i][j]);
    __builtin_amdgcn_s_setprio(0);

    cur += 1; if (cur >= 3) cur -= 3;
  }

  const int sel = n0 >> 10;
#pragma unroll
  for (int i = 0; i < 4; ++i) {
    int row = m0 + wr + i * 16 + g * 4;
    int b = row >> 11, s = row & 2047;
#pragma unroll
    for (int j = 0; j < 4; ++j) {
      int col = n0 + wc + j * 16 + lr;
      float bv = bias[col];
      int nn = col & 1023;
      int h = nn >> 6, hd = nn & 63;
      if (sel == 2) {
        u16 pk[4];
#pragma unroll
        for (int r = 0; r < 4; ++r) pk[r] = f2bf(acc[i][j][r] + bv);
        uint2 pv;
        pv.x = (u32)pk[0] | ((u32)pk[1] << 16);
        pv.y = (u32)pk[2] | ((u32)pk[3] << 16);
        *(uint2*)(Vt + (size_t)((b * 16 + h) * 64 + hd) * 2048 + s) = pv;
      } else {
        u16* dst = (sel == 0) ? Qo : Ko;
#pragma unroll
        for (int r = 0; r < 4; ++r)
          dst[(size_t)((b * 16 + h) * 2048 + s + r) * 64 + hd] =
              f2bf(acc[i][j][r] + bv);
      }
    }
  }
}

// ---------------- proj GEMM: 64x128 tile (R21 — 2 blocks/CU), R18 skeleton
// Waves 2x2: wave tile 32(M) x 64(N); af[2], bfr[4], 8 MFMA/K-step.
// Stage = 3 loads/lane (A 1, B 2). At the wait, outstanding = st(ki)+st(ki+1)
// = 6 -> vmcnt(3) retires st(ki); ki=31 -> vmcnt(0).
__global__ __launch_bounds__(256, 3) void gemm_proj(
    const u16* __restrict__ A, const u16* __restrict__ Bt,
    const float* __restrict__ bias, float* __restrict__ Of) {
  __shared__ alignas(16) u16 As[3][2048];   // 64 rows x 32 k
  __shared__ alignas(16) u16 Bs[3][4096];   // 128 rows x 32 k
  const int tid = threadIdx.x;
  const int wid = tid >> 6, lane = tid & 63;
  const int g = lane >> 4, lr = lane & 15;
  const int m0 = blockIdx.y * 64, n0 = blockIdx.x * 128;
  const int wr = (wid >> 1) * 32, wc = (wid & 1) * 64;

  f32x4 acc[2][4];
#pragma unroll
  for (int i = 0; i < 2; ++i)
#pragma unroll
    for (int j = 0; j < 4; ++j) acc[i][j] = (f32x4){0.f, 0.f, 0.f, 0.f};

  const u16* Ab = A + (size_t)m0 * 1024;
  const u16* Bb = Bt + (size_t)n0 * 1024;

  const int srow = tid >> 2, sc = tid & 3;   // A: 64 rows x 4 chunks = 256
  auto stage = [&](int buf, int kt) {
    {
      int csrc = sc ^ ((srow >> 1) & 3);
      gload16(Ab + (size_t)srow * 1024 + kt + csrc * 8, As[buf] + tid * 8);
    }
#pragma unroll
    for (int i = 0; i < 2; ++i) {            // B: 128 rows x 4 chunks = 512
      int s = tid + i * 256;
      int row = srow + i * 64;
      int csrc = sc ^ ((row >> 1) & 3);
      gload16(Bb + (size_t)row * 1024 + kt + csrc * 8, Bs[buf] + s * 8);
    }
  };

  stage(0, 0);
  stage(1, 32);
  int cur = 0;
  for (int ki = 0; ki < 32; ++ki) {
    if (ki < 31) asm volatile("s_waitcnt vmcnt(3)" ::: "memory");
    else         asm volatile("s_waitcnt vmcnt(0)" ::: "memory");
    __builtin_amdgcn_sched_barrier(0);
    __builtin_amdgcn_s_barrier();
    __builtin_amdgcn_sched_barrier(0);
    if (ki + 2 < 32) {
      int nxt = cur + 2; if (nxt >= 3) nxt -= 3;
      stage(nxt, (ki + 2) * 32);
    }

    bf16x8 af[2], bfr[4];
#pragma unroll
    for (int i = 0; i < 2; ++i) {
      int row = wr + i * 16 + lr;
      int slot = g ^ ((row >> 1) & 3);
      af[i] = *(const bf16x8*)(As[cur] + row * 32 + slot * 8);
    }
#pragma unroll
    for (int j = 0; j < 4; ++j) {
      int row = wc + j * 16 + lr;
      int slot = g ^ ((row >> 1) & 3);
      bfr[j] = *(const bf16x8*)(Bs[cur] + row * 32 + slot * 8);
    }
    __builtin_amdgcn_s_setprio(1);
#pragma unroll
    for (int i = 0; i < 2; ++i)
#pragma unroll
      for (int j = 0; j < 4; ++j)
        acc[i][j] = MFMA16(af[i], bfr[j], acc[i][j]);
    __builtin_amdgcn_s_setprio(0);

    cur += 1; if (cur >= 3) cur -= 3;
  }

#pragma unroll
  for (int i = 0; i < 2; ++i) {
    int row = m0 + wr + i * 16 + g * 4;
#pragma unroll
    for (int j = 0; j < 4; ++j) {
      int col = n0 + wc + j * 16 + lr;
      float bv = bias[col];
#pragma unroll
      for (int r = 0; r < 4; ++r)
        Of[(size_t)(row + r) * 1024 + col] = acc[i][j][r] + bv;
    }
  }
}

// ---------------- flash attention (R17 verbatim — 60.1 µs, verified 3x) ----
// R12 math, 4-buffer ring, ONE barrier/iter.
__global__ __launch_bounds__(256, 2) void attn_k(const u16* __restrict__ Q,
                                                 const u16* __restrict__ K,
                                                 const u16* __restrict__ Vt,
                                                 u16* __restrict__ O) {
  __shared__ alignas(16) u16 Ks[4][4096];   // 4 bufs [kv][hd], chunk-XOR swizzled
  __shared__ alignas(16) u16 Vs[4][4096];   // 4 bufs [hd][kv], chunk-XOR swizzled
  const int tid = threadIdx.x;
  const int wid = tid >> 6, lane = tid & 63;
  const int l31 = lane & 31, b5 = lane >> 5;
  const int p = blockIdx.x;
  const int l = (p & 7) * 64 + (p >> 3);  // XCD chunk swizzle (512 % 8 == 0)
  const int qt = l & 15, bh = l >> 4;
  const u16* Qh = Q + (size_t)bh * 2048 * 64;
  const u16* Kh = K + (size_t)bh * 2048 * 64;
  const u16* Vh = Vt + (size_t)bh * 64 * 2048;

  // Q B-frags FIRST (pinned oldest in the per-lane VMEM queue)
  const int qbase = qt * 128 + wid * 32;
  const u16* qp = Qh + (size_t)(qbase + l31) * 64 + b5 * 8;
  bf16x8 qf[4];
#pragma unroll
  for (int c = 0; c < 4; ++c) qf[c] = *(const bf16x8*)(qp + 16 * c);
  __builtin_amdgcn_sched_barrier(0);

  auto stage = [&](int buf, int t) {
#pragma unroll
    for (int i = 0; i < 2; ++i) {
      int s = tid + i * 256;
      int row = s >> 3, c = (s & 7) ^ (row & 7);
      gload16(Kh + (t * 64 + row) * 64 + c * 8, Ks[buf] + s * 8);
      gload16(Vh + row * 2048 + t * 64 + c * 8, Vs[buf] + s * 8);
    }
  };
  stage(0, 0);
  stage(1, 1);

  f32x16 accO0, accO1;   // rows = hd (crow map), cols = q = lane (lane-local)
#pragma unroll
  for (int r = 0; r < 16; ++r) { accO0[r] = 0.f; accO1[r] = 0.f; }
  float mraw = -1e30f;  // running max for q=l31 (raw-score units)
  float mC = 0.f;       // mraw * C2 (exp2 domain)
  float lsum = 0.f;     // per-lane partial denominator

  const float C2 = 0.125f * 1.44269504088896f;  // SCALE * log2(e)

  int cur = 0;
  for (int t = 0; t < 32; ++t) {
    if (t + 2 < 32) {
      int nxt = cur + 2; if (nxt >= 4) nxt -= 4;
      stage(nxt, t + 2);
    }
    if (t < 30)       asm volatile("s_waitcnt vmcnt(8)" ::: "memory");
    else if (t == 30) asm volatile("s_waitcnt vmcnt(4)" ::: "memory");
    else              asm volatile("s_waitcnt vmcnt(0)" ::: "memory");
    __builtin_amdgcn_sched_barrier(0);
    __builtin_amdgcn_s_barrier();   // all waves' stage(t) complete -> buf ready
    __builtin_amdgcn_sched_barrier(0);

    const u16* Kc = Ks[cur];
    const u16* Vc = Vs[cur];

    // QK^T swapped (A=K, B=Q): same claimed layout on both operands.
    f32x16 s0, s1;
#pragma unroll
    for (int r = 0; r < 16; ++r) { s0[r] = 0.f; s1[r] = 0.f; }
    __builtin_amdgcn_s_setprio(1);
#pragma unroll
    for (int c = 0; c < 4; ++c) {
      bf16x8 k0 = ldsfrag(Kc, l31, 2 * c + b5);
      bf16x8 k1 = ldsfrag(Kc, 32 + l31, 2 * c + b5);
      s0 = MFMA32(k0, qf[c], s0);
      s1 = MFMA32(k1, qf[c], s1);
    }
    __builtin_amdgcn_s_setprio(0);

    // lane-local max over this lane's 32 kv values (q = l31)
    float rmax;
    {
      float a0 = fmaxf(fmaxf(s0[0], s0[1]), fmaxf(s0[2], s0[3]));
      float a1 = fmaxf(fmaxf(s0[4], s0[5]), fmaxf(s0[6], s0[7]));
      float a2 = fmaxf(fmaxf(s0[8], s0[9]), fmaxf(s0[10], s0[11]));
      float a3 = fmaxf(fmaxf(s0[12], s0[13]), fmaxf(s0[14], s0[15]));
      float b0 = fmaxf(fmaxf(s1[0], s1[1]), fmaxf(s1[2], s1[3]));
      float b1 = fmaxf(fmaxf(s1[4], s1[5]), fmaxf(s1[6], s1[7]));
      float b2 = fmaxf(fmaxf(s1[8], s1[9]), fmaxf(s1[10], s1[11]));
      float b3 = fmaxf(fmaxf(s1[12], s1[13]), fmaxf(s1[14], s1[15]));
      rmax = fmaxf(fmaxf(fmaxf(a0, a1), fmaxf(a2, a3)),
                   fmaxf(fmaxf(b0, b1), fmaxf(b2, b3)));
    }
    rmax = fmaxf(rmax, __shfl_xor(rmax, 32));  // combine the two kv-subsets

    // defer-max: accO cols = q = lane -> alpha is LANE-LOCAL.
    if (__any(rmax > mraw + 64.f)) {
      float mn = fmaxf(mraw, rmax);
      float al = EXP2((mraw - mn) * C2);
      mraw = mn;
      mC = mn * C2;
      lsum *= al;
#pragma unroll
      for (int r = 0; r < 16; ++r) {
        accO0[r] *= al;
        accO1[r] *= al;
      }
    }

    // P = exp2(s*C2 - mC); pack reg-adjacent (=kv-adjacent) pairs into words
    u32 w0[8], w1[8];
#pragma unroll
    for (int i = 0; i < 8; ++i) {
      float p0 = EXP2(__builtin_fmaf(s0[2 * i], C2, -mC));
      float p1 = EXP2(__builtin_fmaf(s0[2 * i + 1], C2, -mC));
      float p2 = EXP2(__builtin_fmaf(s1[2 * i], C2, -mC));
      float p3 = EXP2(__builtin_fmaf(s1[2 * i + 1], C2, -mC));
      lsum += (p0 + p1) + (p2 + p3);
      w0[i] = cvtpk(p0, p1);
      w1[i] = cvtpk(p2, p3);
    }

    // PV swapped: per 16-kv chunk c, P B-frag via 2 permlane32_swap; A = Vt rows.
    __builtin_amdgcn_s_setprio(1);
#pragma unroll
    for (int c = 0; c < 4; ++c) {
      u32 a0, a1, b0, b1;
      if (c == 0)      { a0 = w0[0]; b0 = w0[2]; a1 = w0[1]; b1 = w0[3]; }
      else if (c == 1) { a0 = w0[4]; b0 = w0[6]; a1 = w0[5]; b1 = w0[7]; }
      else if (c == 2) { a0 = w1[0]; b0 = w1[2]; a1 = w1[1]; b1 = w1[3]; }
      else             { a0 = w1[4]; b0 = w1[6]; a1 = w1[5]; b1 = w1[7]; }
      swap32(a0, b0);
      swap32(a1, b1);
      uint4 u; u.x = a0; u.y = a1; u.z = b0; u.w = b1;
      bf16x8 pf = __builtin_bit_cast(bf16x8, u);
      bf16x8 v0 = ldsfrag(Vc, l31, 2 * c + b5);
      bf16x8 v1 = ldsfrag(Vc, 32 + l31, 2 * c + b5);
      accO0 = MFMA32(v0, pf, accO0);
      accO1 = MFMA32(v1, pf, accO1);
    }
    __builtin_amdgcn_s_setprio(0);

    // NO second barrier: 4-buffer ring (disjointness proof in R17).
    cur += 1; if (cur >= 4) cur -= 4;
  }

  // finish: denominator for q=l31 is lane-local after one half-exchange
  float ls = lsum + __shfl_xor(lsum, 32);
  float inv = 1.f / ls;
  const int b = bh >> 4, h = bh & 15;
  u16* orow = O + (size_t)(b * 2048 + qbase + l31) * 1024 + h * 64;
#pragma unroll
  for (int rg = 0; rg < 4; ++rg) {
    int hd0 = 8 * rg + 4 * b5;   // accO rows rg*4..rg*4+3 -> hd0..hd0+3
    uint2 o0, o1;
    o0.x = cvtpk(accO0[4 * rg + 0] * inv, accO0[4 * rg + 1] * inv);
    o0.y = cvtpk(accO0[4 * rg + 2] * inv, accO0[4 * rg + 3] * inv);
    o1.x = cvtpk(accO1[4 * rg + 0] * inv, accO1[4 * rg + 1] * inv);
    o1.y = cvtpk(accO1[4 * rg + 2] * inv, accO1[4 * rg + 3] * inv);
    *(uint2*)(orow + hd0) = o0;
    *(uint2*)(orow + 32 + hd0) = o1;
  }
}

extern "C" void kernel_launch(void* const* d_in, const int* in_sizes, int n_in,
                              void* d_out, int out_size, void* d_ws, size_t ws_size,
                              hipStream_t stream) {
  (void)in_sizes; (void)n_in; (void)out_size; (void)ws_size;
  const float* x = (const float*)d_in[0];
  const float* Wqkv = (const float*)d_in[1];
  const float* bqkv = (const float*)d_in[2];
  const float* Wproj = (const float*)d_in[3];
  const float* bproj = (const float*)d_in[4];
  float* out = (float*)d_out;

  char* ws = (char*)d_ws;
  size_t off = 0;
  auto alloc = [&](size_t bytes) {
    void* p = ws + off;
    off += (bytes + 255) & ~(size_t)255;
    return p;
  };
  u16* xb     = (u16*)alloc((size_t)4096 * 1024 * 2);
  u16* Wqkvt  = (u16*)alloc((size_t)3072 * 1024 * 2);
  u16* Wprojt = (u16*)alloc((size_t)1024 * 1024 * 2);
  u16* Qb     = (u16*)alloc((size_t)32 * 2048 * 64 * 2);
  u16* Kb     = (u16*)alloc((size_t)32 * 2048 * 64 * 2);
  u16* Vtb    = (u16*)alloc((size_t)32 * 64 * 2048 * 2);
  u16* AOb    = (u16*)alloc((size_t)4096 * 1024 * 2);

  convert_x<<<2048, 256, 0, stream>>>(x, xb, 4096 * 1024 / 4);
  transpose_w<<<dim3(96, 32), 256, 0, stream>>>(Wqkv, Wqkvt, 1024, 3072);
  transpose_w<<<dim3(32, 32), 256, 0, stream>>>(Wproj, Wprojt, 1024, 1024);
  gemm_qkv<<<dim3(24, 32), 256, 0, stream>>>(xb, Wqkvt, bqkv, Qb, Kb, Vtb);
  attn_k<<<512, 256, 0, stream>>>(Qb, Kb, Vtb, AOb);
  gemm_proj<<<dim3(8, 64), 256, 0, stream>>>(AOb, Wprojt, bproj, out);
}

// Round 22
// 117.558 us; speedup vs baseline: 1.1787x; 1.0491x over previous
//
#include <hip/hip_runtime.h>

typedef __attribute__((ext_vector_type(8))) short bf16x8;
typedef __attribute__((ext_vector_type(4))) float f32x4;
typedef __attribute__((ext_vector_type(16))) float f32x16;
typedef unsigned short u16;
typedef unsigned int u32;

#define MFMA16(a,b,c) __builtin_amdgcn_mfma_f32_16x16x32_bf16((a),(b),(c),0,0,0)
#define MFMA32(a,b,c) __builtin_amdgcn_mfma_f32_32x32x16_bf16((a),(b),(c),0,0,0)

#if __has_builtin(__builtin_amdgcn_exp2f)
#define EXP2(x) __builtin_amdgcn_exp2f(x)
#else
#define EXP2(x) __expf((x) * 0.6931471805599453f)
#endif

// f32 -> bf16 round-to-nearest-even
__device__ __forceinline__ u16 f2bf(float f) {
  u32 u = __builtin_bit_cast(u32, f);
  u += 0x7FFFu + ((u >> 16) & 1u);
  return (u16)(u >> 16);
}

// packed pair f32x2 -> bf16x2 (RNE) in one instruction
__device__ __forceinline__ u32 cvtpk(float lo, float hi) {
  u32 r;
  asm("v_cvt_pk_bf16_f32 %0, %1, %2" : "=v"(r) : "v"(lo), "v"(hi));
  return r;
}

// half-wave register exchange (verified pairing, R12)
__device__ __forceinline__ void swap32(u32& a, u32& b) {
#if __has_builtin(__builtin_amdgcn_permlane32_swap)
  auto r = __builtin_amdgcn_permlane32_swap((int)a, (int)b, false, false);
  a = (u32)r[0];
  b = (u32)r[1];
#else
  u32 pa = __shfl_xor(a, 32), pb = __shfl_xor(b, 32);
  bool lo = ((threadIdx.x & 32) == 0);
  u32 na = lo ? a : pb;
  u32 nb = lo ? pa : b;
  a = na; b = nb;
#endif
}

// async 16B global -> LDS (dest must be wave-uniform base + lane*16)
__device__ __forceinline__ void gload16(const u16* g, u16* l) {
  __builtin_amdgcn_global_load_lds(
      (const __attribute__((address_space(1))) u32*)(const void*)g,
      (__attribute__((address_space(3))) u32*)(void*)l, 16, 0, 0);
}

// swizzled 16B read from a [R][64] bf16 LDS tile (chunk = 8-elem unit)
__device__ __forceinline__ bf16x8 ldsfrag(const u16* lds, int row, int chunk) {
  return *(const bf16x8*)(lds + row * 64 + ((chunk ^ (row & 7)) << 3));
}

// ---------------- fused prep: convert x + transpose both weights ----------
// flat grid 6144: [0,2048) convert x; [2048,5120) Wqkv tiles; [5120,6144) Wproj.
__global__ __launch_bounds__(256) void prep(
    const float* __restrict__ x, u16* __restrict__ xb,
    const float* __restrict__ Wqkv, u16* __restrict__ Wqkvt,
    const float* __restrict__ Wproj, u16* __restrict__ Wprojt) {
  __shared__ float t[32][33];
  const int bx = blockIdx.x;
  if (bx < 2048) {
    // convert 4096x1024 f32 -> bf16, 2 float4 per thread
    int i = bx * 256 + threadIdx.x;
    const int n4 = 4096 * 1024 / 4, stride = 2048 * 256;
    for (; i < n4; i += stride) {
      float4 v = ((const float4*)x)[i];
      uint2 pv;
      pv.x = (u32)f2bf(v.x) | ((u32)f2bf(v.y) << 16);
      pv.y = (u32)f2bf(v.z) | ((u32)f2bf(v.w) << 16);
      ((uint2*)xb)[i] = pv;
    }
    return;
  }
  // transpose W [1024][C] f32 -> Wt [C][1024] bf16
  const float* in;
  u16* out;
  int C, tix;
  if (bx < 5120) { in = Wqkv; out = Wqkvt; C = 3072; tix = bx - 2048; }
  else           { in = Wproj; out = Wprojt; C = 1024; tix = bx - 5120; }
  const int nxt = C / 32;
  int c0 = (tix % nxt) * 32, r0 = (tix / nxt) * 32;
  int tc = threadIdx.x & 31, tr = threadIdx.x >> 5;
#pragma unroll
  for (int j = 0; j < 4; ++j) {
    int r = tr + j * 8;
    t[r][tc] = in[(size_t)(r0 + r) * C + c0 + tc];
  }
  __syncthreads();
#pragma unroll
  for (int j = 0; j < 4; ++j) {
    int cc = tr + j * 8;
    out[(size_t)(c0 + cc) * 1024 + r0 + tc] = f2bf(t[tc][cc]);
  }
}

// ---------------- qkv GEMM: 128x128, 3-buffer, ONE barrier per K-step (R18)
// R22: grid transposed to (32 m-tiles, 24 n-tiles) so consecutive blocks
// share the B-panel (XCD-local B reuse; A streams via L3).
__global__ __launch_bounds__(256, 3) void gemm_qkv(
    const u16* __restrict__ A, const u16* __restrict__ Bt,
    const float* __restrict__ bias,
    u16* __restrict__ Qo, u16* __restrict__ Ko, u16* __restrict__ Vt) {
  __shared__ alignas(16) u16 As[3][4096];
  __shared__ alignas(16) u16 Bs[3][4096];
  const int tid = threadIdx.x;
  const int wid = tid >> 6, lane = tid & 63;
  const int g = lane >> 4, lr = lane & 15;
  const int m0 = blockIdx.x * 128, n0 = blockIdx.y * 128;   // R22: swapped
  const int wr = (wid >> 1) * 64, wc = (wid & 1) * 64;

  f32x4 acc[4][4];
#pragma unroll
  for (int i = 0; i < 4; ++i)
#pragma unroll
    for (int j = 0; j < 4; ++j) acc[i][j] = (f32x4){0.f, 0.f, 0.f, 0.f};

  const u16* Ab = A + (size_t)m0 * 1024;
  const u16* Bb = Bt + (size_t)n0 * 1024;

  const int srow = tid >> 2, sc = tid & 3;
  auto stage = [&](int buf, int kt) {
#pragma unroll
    for (int i = 0; i < 2; ++i) {
      int s = tid + i * 256;
      int row = srow + i * 64;
      int csrc = sc ^ ((row >> 1) & 3);
      gload16(Ab + (size_t)row * 1024 + kt + csrc * 8, As[buf] + s * 8);
      gload16(Bb + (size_t)row * 1024 + kt + csrc * 8, Bs[buf] + s * 8);
    }
  };

  stage(0, 0);
  stage(1, 32);
  int cur = 0;
  for (int ki = 0; ki < 32; ++ki) {
    if (ki < 31) asm volatile("s_waitcnt vmcnt(4)" ::: "memory");
    else         asm volatile("s_waitcnt vmcnt(0)" ::: "memory");
    __builtin_amdgcn_sched_barrier(0);
    __builtin_amdgcn_s_barrier();
    __builtin_amdgcn_sched_barrier(0);
    if (ki + 2 < 32) {
      int nxt = cur + 2; if (nxt >= 3) nxt -= 3;
      stage(nxt, (ki + 2) * 32);
    }

    bf16x8 af[4], bfr[4];
#pragma unroll
    for (int i = 0; i < 4; ++i) {
      int row = wr + i * 16 + lr;
      int slot = g ^ ((row >> 1) & 3);
      af[i] = *(const bf16x8*)(As[cur] + row * 32 + slot * 8);
    }
#pragma unroll
    for (int j = 0; j < 4; ++j) {
      int row = wc + j * 16 + lr;
      int slot = g ^ ((row >> 1) & 3);
      bfr[j] = *(const bf16x8*)(Bs[cur] + row * 32 + slot * 8);
    }
    __builtin_amdgcn_s_setprio(1);
#pragma unroll
    for (int i = 0; i < 4; ++i)
#pragma unroll
      for (int j = 0; j < 4; ++j)
        acc[i][j] = MFMA16(af[i], bfr[j], acc[i][j]);
    __builtin_amdgcn_s_setprio(0);

    cur += 1; if (cur >= 3) cur -= 3;
  }

  const int sel = n0 >> 10;
#pragma unroll
  for (int i = 0; i < 4; ++i) {
    int row = m0 + wr + i * 16 + g * 4;
    int b = row >> 11, s = row & 2047;
#pragma unroll
    for (int j = 0; j < 4; ++j) {
      int col = n0 + wc + j * 16 + lr;
      float bv = bias[col];
      int nn = col & 1023;
      int h = nn >> 6, hd = nn & 63;
      if (sel == 2) {
        u16 pk[4];
#pragma unroll
        for (int r = 0; r < 4; ++r) pk[r] = f2bf(acc[i][j][r] + bv);
        uint2 pv;
        pv.x = (u32)pk[0] | ((u32)pk[1] << 16);
        pv.y = (u32)pk[2] | ((u32)pk[3] << 16);
        *(uint2*)(Vt + (size_t)((b * 16 + h) * 64 + hd) * 2048 + s) = pv;
      } else {
        u16* dst = (sel == 0) ? Qo : Ko;
#pragma unroll
        for (int r = 0; r < 4; ++r)
          dst[(size_t)((b * 16 + h) * 2048 + s + r) * 64 + hd] =
              f2bf(acc[i][j][r] + bv);
      }
    }
  }
}

// ---------------- proj GEMM: 64x128 tile (R21), R18 skeleton ----------
__global__ __launch_bounds__(256, 3) void gemm_proj(
    const u16* __restrict__ A, const u16* __restrict__ Bt,
    const float* __restrict__ bias, float* __restrict__ Of) {
  __shared__ alignas(16) u16 As[3][2048];   // 64 rows x 32 k
  __shared__ alignas(16) u16 Bs[3][4096];   // 128 rows x 32 k
  const int tid = threadIdx.x;
  const int wid = tid >> 6, lane = tid & 63;
  const int g = lane >> 4, lr = lane & 15;
  const int m0 = blockIdx.y * 64, n0 = blockIdx.x * 128;
  const int wr = (wid >> 1) * 32, wc = (wid & 1) * 64;

  f32x4 acc[2][4];
#pragma unroll
  for (int i = 0; i < 2; ++i)
#pragma unroll
    for (int j = 0; j < 4; ++j) acc[i][j] = (f32x4){0.f, 0.f, 0.f, 0.f};

  const u16* Ab = A + (size_t)m0 * 1024;
  const u16* Bb = Bt + (size_t)n0 * 1024;

  const int srow = tid >> 2, sc = tid & 3;
  auto stage = [&](int buf, int kt) {
    {
      int csrc = sc ^ ((srow >> 1) & 3);
      gload16(Ab + (size_t)srow * 1024 + kt + csrc * 8, As[buf] + tid * 8);
    }
#pragma unroll
    for (int i = 0; i < 2; ++i) {
      int s = tid + i * 256;
      int row = srow + i * 64;
      int csrc = sc ^ ((row >> 1) & 3);
      gload16(Bb + (size_t)row * 1024 + kt + csrc * 8, Bs[buf] + s * 8);
    }
  };

  stage(0, 0);
  stage(1, 32);
  int cur = 0;
  for (int ki = 0; ki < 32; ++ki) {
    if (ki < 31) asm volatile("s_waitcnt vmcnt(3)" ::: "memory");
    else         asm volatile("s_waitcnt vmcnt(0)" ::: "memory");
    __builtin_amdgcn_sched_barrier(0);
    __builtin_amdgcn_s_barrier();
    __builtin_amdgcn_sched_barrier(0);
    if (ki + 2 < 32) {
      int nxt = cur + 2; if (nxt >= 3) nxt -= 3;
      stage(nxt, (ki + 2) * 32);
    }

    bf16x8 af[2], bfr[4];
#pragma unroll
    for (int i = 0; i < 2; ++i) {
      int row = wr + i * 16 + lr;
      int slot = g ^ ((row >> 1) & 3);
      af[i] = *(const bf16x8*)(As[cur] + row * 32 + slot * 8);
    }
#pragma unroll
    for (int j = 0; j < 4; ++j) {
      int row = wc + j * 16 + lr;
      int slot = g ^ ((row >> 1) & 3);
      bfr[j] = *(const bf16x8*)(Bs[cur] + row * 32 + slot * 8);
    }
    __builtin_amdgcn_s_setprio(1);
#pragma unroll
    for (int i = 0; i < 2; ++i)
#pragma unroll
      for (int j = 0; j < 4; ++j)
        acc[i][j] = MFMA16(af[i], bfr[j], acc[i][j]);
    __builtin_amdgcn_s_setprio(0);

    cur += 1; if (cur >= 3) cur -= 3;
  }

#pragma unroll
  for (int i = 0; i < 2; ++i) {
    int row = m0 + wr + i * 16 + g * 4;
#pragma unroll
    for (int j = 0; j < 4; ++j) {
      int col = n0 + wc + j * 16 + lr;
      float bv = bias[col];
#pragma unroll
      for (int r = 0; r < 4; ++r)
        Of[(size_t)(row + r) * 1024 + col] = acc[i][j][r] + bv;
    }
  }
}

// ---------------- flash attention (R17 verbatim — 60.1-60.3 µs, verified 4x)
__global__ __launch_bounds__(256, 2) void attn_k(const u16* __restrict__ Q,
                                                 const u16* __restrict__ K,
                                                 const u16* __restrict__ Vt,
                                                 u16* __restrict__ O) {
  __shared__ alignas(16) u16 Ks[4][4096];   // 4 bufs [kv][hd], chunk-XOR swizzled
  __shared__ alignas(16) u16 Vs[4][4096];   // 4 bufs [hd][kv], chunk-XOR swizzled
  const int tid = threadIdx.x;
  const int wid = tid >> 6, lane = tid & 63;
  const int l31 = lane & 31, b5 = lane >> 5;
  const int p = blockIdx.x;
  const int l = (p & 7) * 64 + (p >> 3);  // XCD chunk swizzle (512 % 8 == 0)
  const int qt = l & 15, bh = l >> 4;
  const u16* Qh = Q + (size_t)bh * 2048 * 64;
  const u16* Kh = K + (size_t)bh * 2048 * 64;
  const u16* Vh = Vt + (size_t)bh * 64 * 2048;

  // Q B-frags FIRST (pinned oldest in the per-lane VMEM queue)
  const int qbase = qt * 128 + wid * 32;
  const u16* qp = Qh + (size_t)(qbase + l31) * 64 + b5 * 8;
  bf16x8 qf[4];
#pragma unroll
  for (int c = 0; c < 4; ++c) qf[c] = *(const bf16x8*)(qp + 16 * c);
  __builtin_amdgcn_sched_barrier(0);

  auto stage = [&](int buf, int t) {
#pragma unroll
    for (int i = 0; i < 2; ++i) {
      int s = tid + i * 256;
      int row = s >> 3, c = (s & 7) ^ (row & 7);
      gload16(Kh + (t * 64 + row) * 64 + c * 8, Ks[buf] + s * 8);
      gload16(Vh + row * 2048 + t * 64 + c * 8, Vs[buf] + s * 8);
    }
  };
  stage(0, 0);
  stage(1, 1);

  f32x16 accO0, accO1;   // rows = hd (crow map), cols = q = lane (lane-local)
#pragma unroll
  for (int r = 0; r < 16; ++r) { accO0[r] = 0.f; accO1[r] = 0.f; }
  float mraw = -1e30f;  // running max for q=l31 (raw-score units)
  float mC = 0.f;       // mraw * C2 (exp2 domain)
  float lsum = 0.f;     // per-lane partial denominator

  const float C2 = 0.125f * 1.44269504088896f;  // SCALE * log2(e)

  int cur = 0;
  for (int t = 0; t < 32; ++t) {
    if (t + 2 < 32) {
      int nxt = cur + 2; if (nxt >= 4) nxt -= 4;
      stage(nxt, t + 2);
    }
    if (t < 30)       asm volatile("s_waitcnt vmcnt(8)" ::: "memory");
    else if (t == 30) asm volatile("s_waitcnt vmcnt(4)" ::: "memory");
    else              asm volatile("s_waitcnt vmcnt(0)" ::: "memory");
    __builtin_amdgcn_sched_barrier(0);
    __builtin_amdgcn_s_barrier();   // all waves' stage(t) complete -> buf ready
    __builtin_amdgcn_sched_barrier(0);

    const u16* Kc = Ks[cur];
    const u16* Vc = Vs[cur];

    // QK^T swapped (A=K, B=Q): same claimed layout on both operands.
    f32x16 s0, s1;
#pragma unroll
    for (int r = 0; r < 16; ++r) { s0[r] = 0.f; s1[r] = 0.f; }
    __builtin_amdgcn_s_setprio(1);
#pragma unroll
    for (int c = 0; c < 4; ++c) {
      bf16x8 k0 = ldsfrag(Kc, l31, 2 * c + b5);
      bf16x8 k1 = ldsfrag(Kc, 32 + l31, 2 * c + b5);
      s0 = MFMA32(k0, qf[c], s0);
      s1 = MFMA32(k1, qf[c], s1);
    }
    __builtin_amdgcn_s_setprio(0);

    // lane-local max over this lane's 32 kv values (q = l31)
    float rmax;
    {
      float a0 = fmaxf(fmaxf(s0[0], s0[1]), fmaxf(s0[2], s0[3]));
      float a1 = fmaxf(fmaxf(s0[4], s0[5]), fmaxf(s0[6], s0[7]));
      float a2 = fmaxf(fmaxf(s0[8], s0[9]), fmaxf(s0[10], s0[11]));
      float a3 = fmaxf(fmaxf(s0[12], s0[13]), fmaxf(s0[14], s0[15]));
      float b0 = fmaxf(fmaxf(s1[0], s1[1]), fmaxf(s1[2], s1[3]));
      float b1 = fmaxf(fmaxf(s1[4], s1[5]), fmaxf(s1[6], s1[7]));
      float b2 = fmaxf(fmaxf(s1[8], s1[9]), fmaxf(s1[10], s1[11]));
      float b3 = fmaxf(fmaxf(s1[12], s1[13]), fmaxf(s1[14], s1[15]));
      rmax = fmaxf(fmaxf(fmaxf(a0, a1), fmaxf(a2, a3)),
                   fmaxf(fmaxf(b0, b1), fmaxf(b2, b3)));
    }
    rmax = fmaxf(rmax, __shfl_xor(rmax, 32));  // combine the two kv-subsets

    // defer-max: accO cols = q = lane -> alpha is LANE-LOCAL.
    if (__any(rmax > mraw + 64.f)) {
      float mn = fmaxf(mraw, rmax);
      float al = EXP2((mraw - mn) * C2);
      mraw = mn;
      mC = mn * C2;
      lsum *= al;
#pragma unroll
      for (int r = 0; r < 16; ++r) {
        accO0[r] *= al;
        accO1[r] *= al;
      }
    }

    // P = exp2(s*C2 - mC); pack reg-adjacent (=kv-adjacent) pairs into words
    u32 w0[8], w1[8];
#pragma unroll
    for (int i = 0; i < 8; ++i) {
      float p0 = EXP2(__builtin_fmaf(s0[2 * i], C2, -mC));
      float p1 = EXP2(__builtin_fmaf(s0[2 * i + 1], C2, -mC));
      float p2 = EXP2(__builtin_fmaf(s1[2 * i], C2, -mC));
      float p3 = EXP2(__builtin_fmaf(s1[2 * i + 1], C2, -mC));
      lsum += (p0 + p1) + (p2 + p3);
      w0[i] = cvtpk(p0, p1);
      w1[i] = cvtpk(p2, p3);
    }

    // PV swapped: per 16-kv chunk c, P B-frag via 2 permlane32_swap; A = Vt rows.
    __builtin_amdgcn_s_setprio(1);
#pragma unroll
    for (int c = 0; c < 4; ++c) {
      u32 a0, a1, b0, b1;
      if (c == 0)      { a0 = w0[0]; b0 = w0[2]; a1 = w0[1]; b1 = w0[3]; }
      else if (c == 1) { a0 = w0[4]; b0 = w0[6]; a1 = w0[5]; b1 = w0[7]; }
      else if (c == 2) { a0 = w1[0]; b0 = w1[2]; a1 = w1[1]; b1 = w1[3]; }
      else             { a0 = w1[4]; b0 = w1[6]; a1 = w1[5]; b1 = w1[7]; }
      swap32(a0, b0);
      swap32(a1, b1);
      uint4 u; u.x = a0; u.y = a1; u.z = b0; u.w = b1;
      bf16x8 pf = __builtin_bit_cast(bf16x8, u);
      bf16x8 v0 = ldsfrag(Vc, l31, 2 * c + b5);
      bf16x8 v1 = ldsfrag(Vc, 32 + l31, 2 * c + b5);
      accO0 = MFMA32(v0, pf, accO0);
      accO1 = MFMA32(v1, pf, accO1);
    }
    __builtin_amdgcn_s_setprio(0);

    // NO second barrier: 4-buffer ring (disjointness proof in R17).
    cur += 1; if (cur >= 4) cur -= 4;
  }

  // finish: denominator for q=l31 is lane-local after one half-exchange
  float ls = lsum + __shfl_xor(lsum, 32);
  float inv = 1.f / ls;
  const int b = bh >> 4, h = bh & 15;
  u16* orow = O + (size_t)(b * 2048 + qbase + l31) * 1024 + h * 64;
#pragma unroll
  for (int rg = 0; rg < 4; ++rg) {
    int hd0 = 8 * rg + 4 * b5;   // accO rows rg*4..rg*4+3 -> hd0..hd0+3
    uint2 o0, o1;
    o0.x = cvtpk(accO0[4 * rg + 0] * inv, accO0[4 * rg + 1] * inv);
    o0.y = cvtpk(accO0[4 * rg + 2] * inv, accO0[4 * rg + 3] * inv);
    o1.x = cvtpk(accO1[4 * rg + 0] * inv, accO1[4 * rg + 1] * inv);
    o1.y = cvtpk(accO1[4 * rg + 2] * inv, accO1[4 * rg + 3] * inv);
    *(uint2*)(orow + hd0) = o0;
    *(uint2*)(orow + 32 + hd0) = o1;
  }
}

extern "C" void kernel_launch(void* const* d_in, const int* in_sizes, int n_in,
                              void* d_out, int out_size, void* d_ws, size_t ws_size,
                              hipStream_t stream) {
  (void)in_sizes; (void)n_in; (void)out_size; (void)ws_size;
  const float* x = (const float*)d_in[0];
  const float* Wqkv = (const float*)d_in[1];
  const float* bqkv = (const float*)d_in[2];
  const float* Wproj = (const float*)d_in[3];
  const float* bproj = (const float*)d_in[4];
  float* out = (float*)d_out;

  char* ws = (char*)d_ws;
  size_t off = 0;
  auto alloc = [&](size_t bytes) {
    void* p = ws + off;
    off += (bytes + 255) & ~(size_t)255;
    return p;
  };
  u16* xb     = (u16*)alloc((size_t)4096 * 1024 * 2);
  u16* Wqkvt  = (u16*)alloc((size_t)3072 * 1024 * 2);
  u16* Wprojt = (u16*)alloc((size_t)1024 * 1024 * 2);
  u16* Qb     = (u16*)alloc((size_t)32 * 2048 * 64 * 2);
  u16* Kb     = (u16*)alloc((size_t)32 * 2048 * 64 * 2);
  u16* Vtb    = (u16*)alloc((size_t)32 * 64 * 2048 * 2);
  u16* AOb    = (u16*)alloc((size_t)4096 * 1024 * 2);

  prep<<<6144, 256, 0, stream>>>(x, xb, Wqkv, Wqkvt, Wproj, Wprojt);
  gemm_qkv<<<dim3(32, 24), 256, 0, stream>>>(xb, Wqkvt, bqkv, Qb, Kb, Vtb);
  attn_k<<<512, 256, 0, stream>>>(Qb, Kb, Vtb, AOb);
  gemm_proj<<<dim3(8, 64), 256, 0, stream>>>(AOb, Wprojt, bproj, out);
}